// Round 4
// baseline (12003.252 us; speedup 1.0000x reference)
//
#include <hip/hip_runtime.h>
#include <math.h>

// ESN recurrence: x_t = tanh(u_t @ w_in^T + w_bias + W @ h_{t-1}), h_0 = 0.
// B=8, T=4096, D_RES=1024, D_IN=64, fp32.
//
// 256 WGs (= 8 batches x 32 row-chunks) x 256 threads; 32x1024 W slab in
// registers per WG. Sync protocol v3 (R4):
//  - R2 (9.4 ms) used a shared arrival counter: 32 same-address RMWs
//    serialize at the coherence point (~1.3 us/step).
//  - R3 (11.9 ms) used per-element (value,tag) pairs: 8192 pollers x 32 B
//    poll storm (FETCH 89->368 MB), 2x publish traffic (WRITE 295->393 MB).
//  - R4: 4 B h stores (R2's proven data path) + 32 per-chunk FLAG words in
//    SEPARATE 64 B lines (parallel, no RMW, no same-line contention).
//    Producer: h stores -> per-wave s_waitcnt(0) drain -> barrier -> tid0
//    stores flag=t+1. Consumers: each wave's lanes 0..31 poll the 32 flags
//    (coalesced, one line per lane), __ballot all-set. LDS h double-buffered
//    -> 2 barriers/step total.
// ABA/overwrite safety (2-slot hbuf): a WG writes slot[(t+1)&1] only after
// seeing all flags==t+1, which requires every WG's slot[(t-1)&1] reads to
// have completed (they precede that WG's flag(t+1) store in program order,
// enforced by s_waitcnt + barriers). Placement-independent: all exchange via
// agent-scope atomics; blockIdx%8=batch is an XCD-locality heuristic only.

#define NB        8
#define T_STEPS   4096
#define DRES      1024
#define DIN       64
#define CHUNKS    32      // WGs per batch
#define NTHREADS  256

// ws layout: [hbuf: 2*NB*DRES floats = 64 KB][flags: NB*CHUNKS*16 u32 = 16 KB]
#define HBUF_FLOATS (2 * NB * DRES)
#define FLAG_OFFSET (HBUF_FLOATS * sizeof(float))
#define FLAG_U32S   (NB * CHUNKS * 16)     // 16 u32 = 64 B pad per flag
#define FLAG_BYTES  (FLAG_U32S * sizeof(unsigned int))

__launch_bounds__(NTHREADS, 1)
__global__ void esn_kernel(const float* __restrict__ u,      // [NB][T][DIN]
                           const float* __restrict__ w_in,   // [DRES][DIN]
                           const float* __restrict__ w,      // [DRES][DRES]
                           const float* __restrict__ w_bias, // [DRES]
                           float* __restrict__ out,          // [NB][T][DRES]
                           float* __restrict__ hbuf,         // [2][NB][DRES]
                           unsigned int* __restrict__ flags) // [NB][CHUNKS][16]
{
    const int tid   = threadIdx.x;
    const int b     = blockIdx.x & (NB - 1);   // batch -> XCD affinity heuristic
    const int chunk = blockIdx.x >> 3;         // 0..31 row-chunk
    const int rg    = tid >> 5;                // 0..7 row-group (4 rows each)
    const int mc    = tid & 31;                // 0..31 k-lane
    const int lane  = tid & 63;                // lane within wave
    const int row0  = chunk * 32 + rg * 4;     // first of this thread's 4 rows

    __shared__ float h_lds[2][DRES];           // double-buffered hidden state

    // ---- prologue: weights into registers ----
    float wreg[4][32];                         // wreg[i][j] = W[row0+i][mc+32j]
    #pragma unroll
    for (int i = 0; i < 4; ++i) {
        const float* wr = w + (size_t)(row0 + i) * DRES + mc;
        #pragma unroll
        for (int j = 0; j < 32; ++j)
            wreg[i][j] = wr[32 * j];
    }
    float win0[4], win1[4];                    // w_in[row][2mc], w_in[row][2mc+1]
    #pragma unroll
    for (int i = 0; i < 4; ++i) {
        win0[i] = w_in[(row0 + i) * DIN + 2 * mc];
        win1[i] = w_in[(row0 + i) * DIN + 2 * mc + 1];
    }
    float bias[4];
    #pragma unroll
    for (int i = 0; i < 4; ++i)
        bias[i] = w_bias[row0 + i];

    // h_0 = 0 (step t reads h_lds[t&1])
    #pragma unroll
    for (int k = tid; k < DRES; k += NTHREADS)
        h_lds[0][k] = 0.0f;
    __syncthreads();

    const float* ub = u + (size_t)b * T_STEPS * DIN;
    float2 ucur = *(const float2*)(ub + 2 * mc);   // u_0 slice

    unsigned int* fb = flags + b * CHUNKS * 16;

    #pragma unroll 1
    for (int t = 0; t < T_STEPS; ++t) {
        // prefetch next step's u slice (hidden behind compute+sync)
        const int tn = (t + 1 < T_STEPS) ? (t + 1) : t;
        const float2 unext = *(const float2*)(ub + (size_t)tn * DIN + 2 * mc);

        // input projection + recurrent matvec (W in regs, h bcast from LDS)
        const float* hl = h_lds[t & 1];
        float acc[4];
        #pragma unroll
        for (int i = 0; i < 4; ++i)
            acc[i] = fmaf(win0[i], ucur.x, win1[i] * ucur.y);
        #pragma unroll
        for (int j = 0; j < 32; ++j) {
            const float hv = hl[mc + 32 * j];
            #pragma unroll
            for (int i = 0; i < 4; ++i)
                acc[i] = fmaf(wreg[i][j], hv, acc[i]);
        }

        // butterfly reduce across the 32 k-lanes (stays within 32-lane halves)
        #pragma unroll
        for (int d = 1; d < 32; d <<= 1) {
            #pragma unroll
            for (int i = 0; i < 4; ++i)
                acc[i] += __shfl_xor(acc[i], d, 64);
        }

        // tanh on all lanes (uniform, no divergence)
        float x[4];
        #pragma unroll
        for (int i = 0; i < 4; ++i) {
            const float z = acc[i] + bias[i];
            const float e = __expf(2.0f * z);
            x[i] = 1.0f - 2.0f / (e + 1.0f);
        }

        // ---- publish h FIRST (critical path): 4 B relaxed agent stores ----
        float* hb = hbuf + (size_t)(t & 1) * NB * DRES + (size_t)b * DRES;
        if (mc < 4) {
            const float v = (mc & 2) ? ((mc & 1) ? x[3] : x[2])
                                     : ((mc & 1) ? x[1] : x[0]);
            __hip_atomic_store(hb + row0 + mc, v,
                               __ATOMIC_RELAXED, __HIP_MEMORY_SCOPE_AGENT);
        }

        // output store (off critical path; cached, lazy writeback)
        if (mc == 0) {
            *(float4*)(out + ((size_t)b * T_STEPS + t) * DRES + row0) =
                make_float4(x[0], x[1], x[2], x[3]);
        }
        ucur = unext;

        if (t + 1 == T_STEPS) break;

        const unsigned int tag = (unsigned int)(t + 1);

        // ---- order: this wave's stores acked at coherence point, all waves ----
        __builtin_amdgcn_s_waitcnt(0);
        __syncthreads();

        // ---- signal: one flag word per chunk, own 64 B line (no contention) ----
        if (tid == 0)
            __hip_atomic_store(fb + chunk * 16, tag,
                               __ATOMIC_RELAXED, __HIP_MEMORY_SCOPE_AGENT);

        // ---- every wave polls all 32 chunk flags (lanes 0..31), ballot-all ----
        for (;;) {
            unsigned int v = tag;
            if (lane < 32)
                v = __hip_atomic_load(fb + lane * 16,
                                      __ATOMIC_RELAXED, __HIP_MEMORY_SCOPE_AGENT);
            if (__ballot(v == tag) == ~0ull) break;
            __builtin_amdgcn_s_sleep(1);
        }

        // ---- reload h_t (coalesced 4 B agent loads), restage to other LDS buf ----
        float hv[4];
        #pragma unroll
        for (int i = 0; i < 4; ++i)
            hv[i] = __hip_atomic_load(hb + tid + 256 * i,
                                      __ATOMIC_RELAXED, __HIP_MEMORY_SCOPE_AGENT);
        float* hn = h_lds[(t + 1) & 1];
        #pragma unroll
        for (int i = 0; i < 4; ++i)
            hn[tid + 256 * i] = hv[i];
        __syncthreads();   // restage -> compute RAW (2nd and last barrier)
    }
}

extern "C" void kernel_launch(void* const* d_in, const int* in_sizes, int n_in,
                              void* d_out, int out_size, void* d_ws, size_t ws_size,
                              hipStream_t stream) {
    const float* u      = (const float*)d_in[0];
    const float* w_in   = (const float*)d_in[1];
    const float* w      = (const float*)d_in[2];
    const float* w_bias = (const float*)d_in[3];
    float* out = (float*)d_out;

    float* hbuf = (float*)d_ws;
    unsigned int* flags = (unsigned int*)((char*)d_ws + FLAG_OFFSET);

    // flags must start < 1 (ws is re-poisoned to 0xAA before every call;
    // 0xAAAAAAAA could alias no tag, but zero them for determinism)
    hipMemsetAsync(flags, 0, FLAG_BYTES, stream);

    esn_kernel<<<NB * CHUNKS, NTHREADS, 0, stream>>>(u, w_in, w, w_bias, out,
                                                     hbuf, flags);
}